// Round 3
// baseline (1678.725 us; speedup 1.0000x reference)
//
#include <hip/hip_runtime.h>

typedef unsigned short ushort_t;  // raw bf16 bits
typedef __attribute__((ext_vector_type(4))) float f32x4;
typedef __attribute__((ext_vector_type(8))) short s16x8;
typedef __attribute__((ext_vector_type(4))) short s16x4;

#define MFMA16(a, b, c) __builtin_amdgcn_mfma_f32_16x16x32_bf16((a), (b), (c), 0, 0, 0)

__device__ __forceinline__ float us2f(unsigned short u) {
  union { unsigned int i; float f; } v; v.i = ((unsigned int)u) << 16; return v.f;
}
__device__ __forceinline__ unsigned short f2us(float f) {
  union { float f; unsigned int i; } v; v.f = f;
  unsigned int x = v.i;
  return (unsigned short)((x + 0x7FFFu + ((x >> 16) & 1u)) >> 16);
}
// load 8 consecutive f32, round to 8 bf16
__device__ __forceinline__ s16x8 ld8f(const float* p) {
  f32x4 a = *reinterpret_cast<const f32x4*>(p);
  f32x4 b = *reinterpret_cast<const f32x4*>(p + 4);
  s16x8 r;
  r[0] = (short)f2us(a[0]); r[1] = (short)f2us(a[1]);
  r[2] = (short)f2us(a[2]); r[3] = (short)f2us(a[3]);
  r[4] = (short)f2us(b[0]); r[5] = (short)f2us(b[1]);
  r[6] = (short)f2us(b[2]); r[7] = (short)f2us(b[3]);
  return r;
}
__device__ __forceinline__ float sigm(float x) { return 1.0f / (1.0f + __expf(-x)); }
__device__ __forceinline__ float tanh_f(float x) {
  float e = __expf(-2.0f * fabsf(x));
  float t = (1.0f - e) / (1.0f + e);
  return x < 0.0f ? -t : t;
}

// ---------------------------------------------------------------------------
// f32 -> bf16 weight preconversion into ws:
// [0,196608) whh_q | [196608,393216) whh_p | [393216,425984) q_fc1_w |
// [425984,622592) q_attn_in_w
// ---------------------------------------------------------------------------
__global__ __launch_bounds__(256) void conv_k(
    const float* __restrict__ s0, const float* __restrict__ s1,
    const float* __restrict__ s2, const float* __restrict__ s3,
    ushort_t* __restrict__ d) {
  int i = blockIdx.x * 256 + threadIdx.x;
  if (i >= 155648) return;
  long e = (long)i * 4;
  const float* s; long off;
  if (e < 196608) { s = s0; off = e; }
  else if (e < 393216) { s = s1; off = e - 196608; }
  else if (e < 425984) { s = s2; off = e - 393216; }
  else { s = s3; off = e - 425984; }
  f32x4 v = *reinterpret_cast<const f32x4*>(s + off);
  s16x4 r;
  r[0] = (short)f2us(v[0]); r[1] = (short)f2us(v[1]);
  r[2] = (short)f2us(v[2]); r[3] = (short)f2us(v[3]);
  *reinterpret_cast<s16x4*>(d + e) = r;
}

// ---------------------------------------------------------------------------
// Generic GEMM: out[M,N] = epi(A[M,K] @ W[N,K]^T + bias)
// BN: 128 or 64. EPI: 0 none, 2 mask->0, 3 mask->NEG. ROWSEL: A row r maps to
// (r>>3)*64 + (r&7). AF32/OF32: A / out are f32 (else bf16). W,bias f32.
// ---------------------------------------------------------------------------
template <int BN, int EPI, int ROWSEL, int RELU, int AF32, int OF32>
__global__ __launch_bounds__(256) void gemm_k(
    const void* __restrict__ A_, const float* __restrict__ W,
    const float* __restrict__ bias, const int* __restrict__ em,
    void* __restrict__ out_, int M, int N, int K) {
  constexpr int NF = (BN == 128) ? 4 : 2;
  const float* Af = (const float*)A_;
  const ushort_t* Ab = (const ushort_t*)A_;
  float* outf = (float*)out_;
  ushort_t* outb = (ushort_t*)out_;
  __shared__ ushort_t As[128 * 40];
  __shared__ ushort_t Ws[BN * 40];
  const int tid = threadIdx.x;
  const int lane = tid & 63;
  const int wid = tid >> 6;
  const int wm = wid & 1, wn = wid >> 1;
  const int m0 = blockIdx.x * 128;
  const int n0 = blockIdx.y * BN;
  const int fr = lane & 15;
  const int kb = (lane >> 4) * 8;

  f32x4 acc[4][NF];
#pragma unroll
  for (int i = 0; i < 4; i++)
#pragma unroll
    for (int j = 0; j < NF; j++) acc[i][j] = (f32x4){0.f, 0.f, 0.f, 0.f};

  for (int k0 = 0; k0 < K; k0 += 32) {
    __syncthreads();
    for (int c = tid; c < 512; c += 256) {
      int row = c >> 2, kc = (c & 3) * 8;
      int gr = m0 + row;
      long ar = ROWSEL ? ((long)(gr >> 3) * 64 + (gr & 7)) : (long)gr;
      s16x8 vv;
      if (AF32) vv = ld8f(&Af[ar * (long)K + k0 + kc]);
      else vv = *reinterpret_cast<const s16x8*>(&Ab[ar * (long)K + k0 + kc]);
      *reinterpret_cast<s16x8*>(&As[row * 40 + kc]) = vv;
    }
    for (int c = tid; c < BN * 4; c += 256) {
      int row = c >> 2, kc = (c & 3) * 8;
      *reinterpret_cast<s16x8*>(&Ws[row * 40 + kc]) =
          ld8f(&W[(long)(n0 + row) * K + k0 + kc]);
    }
    __syncthreads();
    s16x8 af[4], wf[NF];
#pragma unroll
    for (int mi = 0; mi < 4; mi++)
      af[mi] = *reinterpret_cast<const s16x8*>(&As[(wm * 64 + mi * 16 + fr) * 40 + kb]);
#pragma unroll
    for (int ni = 0; ni < NF; ni++)
      wf[ni] = *reinterpret_cast<const s16x8*>(&Ws[(wn * (BN / 2) + ni * 16 + fr) * 40 + kb]);
#pragma unroll
    for (int mi = 0; mi < 4; mi++)
#pragma unroll
      for (int ni = 0; ni < NF; ni++) acc[mi][ni] = MFMA16(af[mi], wf[ni], acc[mi][ni]);
  }

  const int rb = (lane >> 4) * 4;
#pragma unroll
  for (int ni = 0; ni < NF; ni++) {
    int col = n0 + wn * (BN / 2) + ni * 16 + fr;
    float bv = bias[col];
#pragma unroll
    for (int mi = 0; mi < 4; mi++) {
#pragma unroll
      for (int rr = 0; rr < 4; rr++) {
        int row = m0 + wm * 64 + mi * 16 + rb + rr;
        float v = acc[mi][ni][rr] + bv;
        if (RELU) v = fmaxf(v, 0.0f);
        if (EPI == 2 || EPI == 3) {
          if (em[(long)(row >> 3) * 64 + (row & 7)] != 0) v = (EPI == 2) ? 0.0f : -1.0e10f;
        }
        if (OF32) outf[(long)row * N + col] = v;
        else outb[(long)row * N + col] = f2us(v);
      }
    }
  }
}

// ---------------------------------------------------------------------------
// Fused q-module front-end, one block per batch b in [0,2048):
// x1 = relu(e @ fc1^T + b1); q = x1[:8] @ Wq^T / 8; k,v = x1 @ Wk^T, Wv^T;
// masked softmax(q k^T) @ v -> attn_out[b*8..][256] (bf16 ws).
// ent f32; fc1w/inw pre-converted bf16; fc1b f32.
// ---------------------------------------------------------------------------
__global__ __launch_bounds__(512) void attn_k(
    const float* __restrict__ ent, const int* __restrict__ obs,
    const ushort_t* __restrict__ fc1w, const float* __restrict__ fc1b,
    const ushort_t* __restrict__ inw, ushort_t* __restrict__ attn_out) {
  __shared__ ushort_t x1s[64 * 264];
  __shared__ ushort_t ks[64 * 264];
  __shared__ ushort_t vs[64 * 264];
  __shared__ ushort_t wbuf[256 * 40];
  __shared__ ushort_t es[64 * 136];
  __shared__ float qs[8 * 256];
  __shared__ float lg[32 * 64];
  __shared__ int oms[512];

  const long b = blockIdx.x;
  const int tid = threadIdx.x;
  const int lane = tid & 63, wid = tid >> 6;
  const int mf = wid & 3, nh = wid >> 2;
  const int fr = lane & 15, kb = (lane >> 4) * 8, rb = (lane >> 4) * 4;

  oms[tid] = obs[b * 4096 + tid];  // rows a=0..7 of obs_mask[b]
  for (int c = tid; c < 1024; c += 512) {
    int row = c >> 4, kc = (c & 15) * 8;
    *reinterpret_cast<s16x8*>(&es[row * 136 + kc]) =
        ld8f(&ent[b * 8192 + row * 128 + kc]);
  }
  __syncthreads();

  // ---- x1 = relu(e @ fc1^T + b1) ----
  {
    f32x4 a1[8];
#pragma unroll
    for (int i = 0; i < 8; i++) a1[i] = (f32x4){0.f, 0.f, 0.f, 0.f};
    for (int k0 = 0; k0 < 128; k0 += 32) {
      __syncthreads();
      for (int c = tid; c < 1024; c += 512) {
        int row = c >> 2, kc = (c & 3) * 8;
        *reinterpret_cast<s16x8*>(&wbuf[row * 40 + kc]) =
            *reinterpret_cast<const s16x8*>(&fc1w[row * 128 + k0 + kc]);
      }
      __syncthreads();
      s16x8 af = *reinterpret_cast<const s16x8*>(&es[(mf * 16 + fr) * 136 + k0 + kb]);
#pragma unroll
      for (int ni = 0; ni < 8; ni++) {
        s16x8 wf = *reinterpret_cast<const s16x8*>(&wbuf[(nh * 128 + ni * 16 + fr) * 40 + kb]);
        a1[ni] = MFMA16(af, wf, a1[ni]);
      }
    }
#pragma unroll
    for (int ni = 0; ni < 8; ni++) {
      int col = nh * 128 + ni * 16 + fr;
      float bv = fc1b[col];
#pragma unroll
      for (int rr = 0; rr < 4; rr++) {
        int row = mf * 16 + rb + rr;
        x1s[row * 264 + col] = f2us(fmaxf(a1[ni][rr] + bv, 0.0f));
      }
    }
  }
  // ---- k = x1 @ Wk^T ----
  {
    f32x4 a2[8];
#pragma unroll
    for (int i = 0; i < 8; i++) a2[i] = (f32x4){0.f, 0.f, 0.f, 0.f};
    for (int k0 = 0; k0 < 256; k0 += 32) {
      __syncthreads();
      for (int c = tid; c < 1024; c += 512) {
        int row = c >> 2, kc = (c & 3) * 8;
        *reinterpret_cast<s16x8*>(&wbuf[row * 40 + kc]) =
            *reinterpret_cast<const s16x8*>(&inw[65536 + row * 256 + k0 + kc]);
      }
      __syncthreads();
      s16x8 af = *reinterpret_cast<const s16x8*>(&x1s[(mf * 16 + fr) * 264 + k0 + kb]);
#pragma unroll
      for (int ni = 0; ni < 8; ni++) {
        s16x8 wf = *reinterpret_cast<const s16x8*>(&wbuf[(nh * 128 + ni * 16 + fr) * 40 + kb]);
        a2[ni] = MFMA16(af, wf, a2[ni]);
      }
    }
#pragma unroll
    for (int ni = 0; ni < 8; ni++) {
      int col = nh * 128 + ni * 16 + fr;
#pragma unroll
      for (int rr = 0; rr < 4; rr++) ks[(mf * 16 + rb + rr) * 264 + col] = f2us(a2[ni][rr]);
    }
  }
  // ---- v = x1 @ Wv^T ----
  {
    f32x4 a3[8];
#pragma unroll
    for (int i = 0; i < 8; i++) a3[i] = (f32x4){0.f, 0.f, 0.f, 0.f};
    for (int k0 = 0; k0 < 256; k0 += 32) {
      __syncthreads();
      for (int c = tid; c < 1024; c += 512) {
        int row = c >> 2, kc = (c & 3) * 8;
        *reinterpret_cast<s16x8*>(&wbuf[row * 40 + kc]) =
            *reinterpret_cast<const s16x8*>(&inw[131072 + row * 256 + k0 + kc]);
      }
      __syncthreads();
      s16x8 af = *reinterpret_cast<const s16x8*>(&x1s[(mf * 16 + fr) * 264 + k0 + kb]);
#pragma unroll
      for (int ni = 0; ni < 8; ni++) {
        s16x8 wf = *reinterpret_cast<const s16x8*>(&wbuf[(nh * 128 + ni * 16 + fr) * 40 + kb]);
        a3[ni] = MFMA16(af, wf, a3[ni]);
      }
    }
#pragma unroll
    for (int ni = 0; ni < 8; ni++) {
      int col = nh * 128 + ni * 16 + fr;
#pragma unroll
      for (int rr = 0; rr < 4; rr++) vs[(mf * 16 + rb + rr) * 264 + col] = f2us(a3[ni][rr]);
    }
  }
  // ---- q = x1[0:16] @ Wq^T (rows 0..7 used), scaled by 1/8 ----
  {
    f32x4 aq[2];
    aq[0] = (f32x4){0.f, 0.f, 0.f, 0.f};
    aq[1] = (f32x4){0.f, 0.f, 0.f, 0.f};
    for (int k0 = 0; k0 < 256; k0 += 32) {
      __syncthreads();
      for (int c = tid; c < 1024; c += 512) {
        int row = c >> 2, kc = (c & 3) * 8;
        *reinterpret_cast<s16x8*>(&wbuf[row * 40 + kc]) =
            *reinterpret_cast<const s16x8*>(&inw[row * 256 + k0 + kc]);
      }
      __syncthreads();
      s16x8 af = *reinterpret_cast<const s16x8*>(&x1s[fr * 264 + k0 + kb]);
#pragma unroll
      for (int i = 0; i < 2; i++) {
        int nf2 = wid * 2 + i;
        s16x8 wf = *reinterpret_cast<const s16x8*>(&wbuf[(nf2 * 16 + fr) * 40 + kb]);
        aq[i] = MFMA16(af, wf, aq[i]);
      }
    }
#pragma unroll
    for (int i = 0; i < 2; i++) {
#pragma unroll
      for (int rr = 0; rr < 4; rr++) {
        int row = rb + rr;
        if (row < 8) qs[row * 256 + (wid * 2 + i) * 16 + fr] = aq[i][rr] * 0.125f;
      }
    }
  }
  __syncthreads();

  // ---- logits[a][h][e] with mask ----
  for (int i = 0; i < 4; i++) {
    int idx = tid + 512 * i;
    int a = idx >> 8, h = (idx >> 6) & 3, e = idx & 63;
    const float* qrow = &qs[a * 256 + h * 64];
    const ushort_t* krow = &ks[e * 264 + h * 64];
    float s = 0.0f;
    for (int d = 0; d < 64; d++) s += qrow[d] * us2f(krow[d]);
    lg[(a * 4 + h) * 64 + e] = (oms[a * 64 + e] != 0) ? -1.0e30f : s;
  }
  __syncthreads();
  // ---- softmax over e, dead rows -> 0 ----
  if (tid < 32) {
    int a = tid >> 2;
    float* row = &lg[tid * 64];
    bool dead = true;
    for (int e = 0; e < 64; e++)
      if (oms[a * 64 + e] == 0) { dead = false; break; }
    if (dead) {
      for (int e = 0; e < 64; e++) row[e] = 0.0f;
    } else {
      float mx = -1.0e30f;
      for (int e = 0; e < 64; e++) mx = fmaxf(mx, row[e]);
      float sum = 0.0f;
      for (int e = 0; e < 64; e++) { float ex = __expf(row[e] - mx); row[e] = ex; sum += ex; }
      float inv = 1.0f / sum;
      for (int e = 0; e < 64; e++) row[e] *= inv;
    }
  }
  __syncthreads();
  // ---- out[a][d] = sum_e w[a][h(d)][e] * v[e][d] ----
  for (int i = 0; i < 4; i++) {
    int idx = tid + 512 * i;
    int a = idx >> 8, d = idx & 255, h = d >> 6;
    const float* wrow = &lg[(a * 4 + h) * 64];
    float s = 0.0f;
    for (int e = 0; e < 64; e++) s += wrow[e] * us2f(vs[e * 264 + d]);
    attn_out[((long)b * 8 + a) * 256 + d] = f2us(s);
  }
}

// ---------------------------------------------------------------------------
// GRU scan. 8 blocks: (module, row-tile of 64 of the 256 state rows).
// gi bf16 (ws), whh bf16 (pre-converted, re-staged from L2 each step),
// bhh/h0 f32 (inputs), hs f32 (d_out).
// ---------------------------------------------------------------------------
__global__ __launch_bounds__(512) void gru_k(
    const ushort_t* __restrict__ gi_q, const ushort_t* __restrict__ gi_p,
    const ushort_t* __restrict__ whh_q, const ushort_t* __restrict__ whh_p,
    const float* __restrict__ bhh_q, const float* __restrict__ bhh_p,
    const float* __restrict__ h0_q, const float* __restrict__ h0_p,
    float* __restrict__ hs_q, float* __restrict__ hs_p) {
  __shared__ ushort_t hbf[64 * 264];
  __shared__ ushort_t wst[768 * 40];
  const int mdl = blockIdx.x >> 2;
  const int rt = blockIdx.x & 3;
  const ushort_t* gi = mdl ? gi_p : gi_q;
  const ushort_t* whh = mdl ? whh_p : whh_q;
  const float* bhh = mdl ? bhh_p : bhh_q;
  const float* h0 = mdl ? h0_p : h0_q;
  float* hs = mdl ? hs_p : hs_q;

  const int tid = threadIdx.x;
  const int lane = tid & 63, wid = tid >> 6;
  const int mf = wid & 3, gh = wid >> 2;
  const int fr = lane & 15, kb = (lane >> 4) * 8, rb = (lane >> 4) * 4;

  float h[8][4];
  float bh[3][8];
#pragma unroll
  for (int jf = 0; jf < 8; jf++) {
    int col = gh * 128 + jf * 16 + fr;
#pragma unroll
    for (int rr = 0; rr < 4; rr++) {
      int row = rt * 64 + mf * 16 + rb + rr;
      h[jf][rr] = h0[row * 256 + col];
    }
#pragma unroll
    for (int g = 0; g < 3; g++) bh[g][jf] = bhh[g * 256 + col];
  }

  for (int t = 0; t < 64; t++) {
#pragma unroll
    for (int jf = 0; jf < 8; jf++) {
      int col = gh * 128 + jf * 16 + fr;
#pragma unroll
      for (int rr = 0; rr < 4; rr++) hbf[(mf * 16 + rb + rr) * 264 + col] = f2us(h[jf][rr]);
    }
    __syncthreads();

    f32x4 acc[3][8];
#pragma unroll
    for (int g = 0; g < 3; g++)
#pragma unroll
      for (int jf = 0; jf < 8; jf++) acc[g][jf] = (f32x4){0.f, 0.f, 0.f, 0.f};

    for (int k0 = 0; k0 < 256; k0 += 32) {
      for (int c = tid; c < 3072; c += 512) {
        int row = c >> 2, kc = (c & 3) * 8;
        *reinterpret_cast<s16x8*>(&wst[row * 40 + kc]) =
            *reinterpret_cast<const s16x8*>(&whh[row * 256 + k0 + kc]);
      }
      __syncthreads();
      s16x8 af = *reinterpret_cast<const s16x8*>(&hbf[(mf * 16 + fr) * 264 + k0 + kb]);
#pragma unroll
      for (int g = 0; g < 3; g++)
#pragma unroll
        for (int jf = 0; jf < 8; jf++) {
          s16x8 wf = *reinterpret_cast<const s16x8*>(
              &wst[(g * 256 + gh * 128 + jf * 16 + fr) * 40 + kb]);
          acc[g][jf] = MFMA16(af, wf, acc[g][jf]);
        }
      __syncthreads();
    }

#pragma unroll
    for (int jf = 0; jf < 8; jf++) {
      int col = gh * 128 + jf * 16 + fr;
#pragma unroll
      for (int rr = 0; rr < 4; rr++) {
        int row = rt * 64 + mf * 16 + rb + rr;
        int bs = row >> 3, na = row & 7;
        long gr = (long)(bs * 64 + t) * 8 + na;
        float ir = us2f(gi[gr * 768 + col]);
        float iz = us2f(gi[gr * 768 + 256 + col]);
        float in_ = us2f(gi[gr * 768 + 512 + col]);
        float r_ = sigm(ir + acc[0][jf][rr] + bh[0][jf]);
        float z_ = sigm(iz + acc[1][jf][rr] + bh[1][jf]);
        float n_ = tanh_f(in_ + r_ * (acc[2][jf][rr] + bh[2][jf]));
        float hn = (1.0f - z_) * n_ + z_ * h[jf][rr];
        h[jf][rr] = hn;
        hs[gr * 256 + col] = hn;
      }
    }
  }
}

// ---------------------------------------------------------------------------
extern "C" void kernel_launch(void* const* d_in, const int* in_sizes, int n_in,
                              void* d_out, int out_size, void* d_ws, size_t ws_size,
                              hipStream_t stream) {
  (void)in_sizes; (void)n_in; (void)out_size; (void)ws_size;

  const float* entities = (const float*)d_in[0];
  const int* obs = (const int*)d_in[1];
  const int* em = (const int*)d_in[2];
  const float* hidq = (const float*)d_in[3];
  const float* hidp = (const float*)d_in[4];
  const float* q_fc1_w = (const float*)d_in[5];
  const float* q_fc1_b = (const float*)d_in[6];
  const float* q_fc2_w = (const float*)d_in[7];
  const float* q_fc2_b = (const float*)d_in[8];
  const float* q_wih = (const float*)d_in[9];
  const float* q_whh = (const float*)d_in[10];
  const float* q_bih = (const float*)d_in[11];
  const float* q_bhh = (const float*)d_in[12];
  const float* q_fcq_w = (const float*)d_in[13];
  const float* q_fcq_b = (const float*)d_in[14];
  const float* q_fcpi_w = (const float*)d_in[15];
  const float* q_fcpi_b = (const float*)d_in[16];
  const float* p_fc1_w = (const float*)d_in[17];
  const float* p_fc1_b = (const float*)d_in[18];
  const float* p_fc2_w = (const float*)d_in[19];
  const float* p_fc2_b = (const float*)d_in[20];
  const float* p_wih = (const float*)d_in[21];
  const float* p_whh = (const float*)d_in[22];
  const float* p_bih = (const float*)d_in[23];
  const float* p_bhh = (const float*)d_in[24];
  const float* p_fcpi_w = (const float*)d_in[27];
  const float* p_fcpi_b = (const float*)d_in[28];
  const float* inw = (const float*)d_in[29];
  const float* outw = (const float*)d_in[30];
  const float* outb = (const float*)d_in[31];

  // ws (bf16 elems): R0 | R1 | giq | gip | whhq_bf | whhp_bf | fc1w_bf | inw_bf
  ushort_t* ws = (ushort_t*)d_ws;
  ushort_t* R0 = ws;                         // 4,194,304
  ushort_t* R1 = ws + 4194304l;              // 4,194,304
  ushort_t* giq = ws + 8388608l;             // 12,582,912
  ushort_t* gip = ws + 20971520l;            // 12,582,912
  ushort_t* wcv = ws + 33554432l;            // 622,592 (see conv_k layout)
  ushort_t* wbq = wcv;                       // whh_q bf16
  ushort_t* wbp = wcv + 196608l;             // whh_p bf16
  ushort_t* wf1 = wcv + 393216l;             // q_fc1_w bf16
  ushort_t* win = wcv + 425984l;             // q_attn_in_w bf16

  // Outputs (f32): q, pi, pi_avg (1,048,576 ea), h_q, h_pi (4,194,304 ea)
  float* out = (float*)d_out;
  float* o_q = out;
  float* o_pi = out + 1048576l;
  float* o_piA = out + 2097152l;
  float* o_hq = out + 3145728l;
  float* o_hp = out + 7340032l;

  // 0) pre-convert hot weights to bf16
  conv_k<<<608, 256, 0, stream>>>(q_whh, p_whh, q_fc1_w, inw, wcv);
  // 1) q-module front-end (fused fc1 + qkv + attention) -> R0 (bf16)
  attn_k<<<2048, 512, 0, stream>>>(entities, obs, wf1, q_fc1_b, win, R0);
  // 2) x2 = mask0(attn @ outw^T + outb) -> R1
  gemm_k<128, 2, 0, 0, 0, 0><<<dim3(128, 2), 256, 0, stream>>>(R0, outw, outb, em, R1, 16384, 256, 256);
  // 3) x3q = relu(x2 @ fc2^T + b) -> R0
  gemm_k<128, 0, 0, 1, 0, 0><<<dim3(128, 2), 256, 0, stream>>>(R1, q_fc2_w, q_fc2_b, em, R0, 16384, 256, 256);
  // 4) gi_q = x3q @ wih^T + bih
  gemm_k<128, 0, 0, 0, 0, 0><<<dim3(128, 6), 256, 0, stream>>>(R0, q_wih, q_bih, em, giq, 16384, 768, 256);
  // 5) x1p = relu(e[:, :8] @ fc1^T + b) -> R1   (A = f32 entities, ROWSEL)
  gemm_k<128, 0, 1, 1, 1, 0><<<dim3(128, 2), 256, 0, stream>>>(entities, p_fc1_w, p_fc1_b, em, R1, 16384, 256, 128);
  // 6) x3p = relu(x1p @ fc2^T + b) -> R0
  gemm_k<128, 0, 0, 1, 0, 0><<<dim3(128, 2), 256, 0, stream>>>(R1, p_fc2_w, p_fc2_b, em, R0, 16384, 256, 256);
  // 7) gi_p
  gemm_k<128, 0, 0, 0, 0, 0><<<dim3(128, 6), 256, 0, stream>>>(R0, p_wih, p_bih, em, gip, 16384, 768, 256);
  // 8) GRU scan -> h_q, h_pi (f32 outputs)
  gru_k<<<8, 512, 0, stream>>>(giq, gip, wbq, wbp, q_bhh, p_bhh, hidq, hidp, o_hq, o_hp);
  // 9) heads (A = f32 hs, f32 out)
  gemm_k<64, 2, 0, 0, 1, 1><<<dim3(128, 1), 256, 0, stream>>>(o_hq, q_fcq_w, q_fcq_b, em, o_q, 16384, 64, 256);
  gemm_k<64, 3, 0, 0, 1, 1><<<dim3(128, 1), 256, 0, stream>>>(o_hq, q_fcpi_w, q_fcpi_b, em, o_pi, 16384, 64, 256);
  gemm_k<64, 3, 0, 0, 1, 1><<<dim3(128, 1), 256, 0, stream>>>(o_hp, p_fcpi_w, p_fcpi_b, em, o_piA, 16384, 64, 256);
}

// Round 4
// 1235.090 us; speedup vs baseline: 1.3592x; 1.3592x over previous
//
#include <hip/hip_runtime.h>

typedef unsigned short ushort_t;  // raw bf16 bits
typedef __attribute__((ext_vector_type(4))) float f32x4;
typedef __attribute__((ext_vector_type(8))) short s16x8;
typedef __attribute__((ext_vector_type(4))) short s16x4;

#define MFMA16(a, b, c) __builtin_amdgcn_mfma_f32_16x16x32_bf16((a), (b), (c), 0, 0, 0)

__device__ __forceinline__ float us2f(unsigned short u) {
  union { unsigned int i; float f; } v; v.i = ((unsigned int)u) << 16; return v.f;
}
__device__ __forceinline__ unsigned short f2us(float f) {
  union { float f; unsigned int i; } v; v.f = f;
  unsigned int x = v.i;
  return (unsigned short)((x + 0x7FFFu + ((x >> 16) & 1u)) >> 16);
}
// load 8 consecutive f32, round to 8 bf16
__device__ __forceinline__ s16x8 ld8f(const float* p) {
  f32x4 a = *reinterpret_cast<const f32x4*>(p);
  f32x4 b = *reinterpret_cast<const f32x4*>(p + 4);
  s16x8 r;
  r[0] = (short)f2us(a[0]); r[1] = (short)f2us(a[1]);
  r[2] = (short)f2us(a[2]); r[3] = (short)f2us(a[3]);
  r[4] = (short)f2us(b[0]); r[5] = (short)f2us(b[1]);
  r[6] = (short)f2us(b[2]); r[7] = (short)f2us(b[3]);
  return r;
}
__device__ __forceinline__ float sigm(float x) { return 1.0f / (1.0f + __expf(-x)); }
__device__ __forceinline__ float tanh_f(float x) {
  float e = __expf(-2.0f * fabsf(x));
  float t = (1.0f - e) / (1.0f + e);
  return x < 0.0f ? -t : t;
}

// ---------------------------------------------------------------------------
// f32 -> bf16 weight preconversion into ws:
// [0,196608) whh_q | [196608,393216) whh_p | [393216,425984) q_fc1_w |
// [425984,622592) q_attn_in_w
// ---------------------------------------------------------------------------
__global__ __launch_bounds__(256) void conv_k(
    const float* __restrict__ s0, const float* __restrict__ s1,
    const float* __restrict__ s2, const float* __restrict__ s3,
    ushort_t* __restrict__ d) {
  int i = blockIdx.x * 256 + threadIdx.x;
  if (i >= 155648) return;
  long e = (long)i * 4;
  const float* s; long off;
  if (e < 196608) { s = s0; off = e; }
  else if (e < 393216) { s = s1; off = e - 196608; }
  else if (e < 425984) { s = s2; off = e - 393216; }
  else { s = s3; off = e - 425984; }
  f32x4 v = *reinterpret_cast<const f32x4*>(s + off);
  s16x4 r;
  r[0] = (short)f2us(v[0]); r[1] = (short)f2us(v[1]);
  r[2] = (short)f2us(v[2]); r[3] = (short)f2us(v[3]);
  *reinterpret_cast<s16x4*>(d + e) = r;
}

// ---------------------------------------------------------------------------
// Generic GEMM: out[M,N] = epi(A[M,K] @ W[N,K]^T + bias)
// ---------------------------------------------------------------------------
template <int BN, int EPI, int ROWSEL, int RELU, int AF32, int OF32>
__global__ __launch_bounds__(256) void gemm_k(
    const void* __restrict__ A_, const float* __restrict__ W,
    const float* __restrict__ bias, const int* __restrict__ em,
    void* __restrict__ out_, int M, int N, int K) {
  constexpr int NF = (BN == 128) ? 4 : 2;
  const float* Af = (const float*)A_;
  const ushort_t* Ab = (const ushort_t*)A_;
  float* outf = (float*)out_;
  ushort_t* outb = (ushort_t*)out_;
  __shared__ ushort_t As[128 * 40];
  __shared__ ushort_t Ws[BN * 40];
  const int tid = threadIdx.x;
  const int lane = tid & 63;
  const int wid = tid >> 6;
  const int wm = wid & 1, wn = wid >> 1;
  const int m0 = blockIdx.x * 128;
  const int n0 = blockIdx.y * BN;
  const int fr = lane & 15;
  const int kb = (lane >> 4) * 8;

  f32x4 acc[4][NF];
#pragma unroll
  for (int i = 0; i < 4; i++)
#pragma unroll
    for (int j = 0; j < NF; j++) acc[i][j] = (f32x4){0.f, 0.f, 0.f, 0.f};

  for (int k0 = 0; k0 < K; k0 += 32) {
    __syncthreads();
    for (int c = tid; c < 512; c += 256) {
      int row = c >> 2, kc = (c & 3) * 8;
      int gr = m0 + row;
      long ar = ROWSEL ? ((long)(gr >> 3) * 64 + (gr & 7)) : (long)gr;
      s16x8 vv;
      if (AF32) vv = ld8f(&Af[ar * (long)K + k0 + kc]);
      else vv = *reinterpret_cast<const s16x8*>(&Ab[ar * (long)K + k0 + kc]);
      *reinterpret_cast<s16x8*>(&As[row * 40 + kc]) = vv;
    }
    for (int c = tid; c < BN * 4; c += 256) {
      int row = c >> 2, kc = (c & 3) * 8;
      *reinterpret_cast<s16x8*>(&Ws[row * 40 + kc]) =
          ld8f(&W[(long)(n0 + row) * K + k0 + kc]);
    }
    __syncthreads();
    s16x8 af[4], wf[NF];
#pragma unroll
    for (int mi = 0; mi < 4; mi++)
      af[mi] = *reinterpret_cast<const s16x8*>(&As[(wm * 64 + mi * 16 + fr) * 40 + kb]);
#pragma unroll
    for (int ni = 0; ni < NF; ni++)
      wf[ni] = *reinterpret_cast<const s16x8*>(&Ws[(wn * (BN / 2) + ni * 16 + fr) * 40 + kb]);
#pragma unroll
    for (int mi = 0; mi < 4; mi++)
#pragma unroll
      for (int ni = 0; ni < NF; ni++) acc[mi][ni] = MFMA16(af[mi], wf[ni], acc[mi][ni]);
  }

  const int rb = (lane >> 4) * 4;
#pragma unroll
  for (int ni = 0; ni < NF; ni++) {
    int col = n0 + wn * (BN / 2) + ni * 16 + fr;
    float bv = bias[col];
#pragma unroll
    for (int mi = 0; mi < 4; mi++) {
#pragma unroll
      for (int rr = 0; rr < 4; rr++) {
        int row = m0 + wm * 64 + mi * 16 + rb + rr;
        float v = acc[mi][ni][rr] + bv;
        if (RELU) v = fmaxf(v, 0.0f);
        if (EPI == 2 || EPI == 3) {
          if (em[(long)(row >> 3) * 64 + (row & 7)] != 0) v = (EPI == 2) ? 0.0f : -1.0e10f;
        }
        if (OF32) outf[(long)row * N + col] = v;
        else outb[(long)row * N + col] = f2us(v);
      }
    }
  }
}

// ---------------------------------------------------------------------------
// Fused q-module front-end (unchanged from round 3, passing)
// ---------------------------------------------------------------------------
__global__ __launch_bounds__(512) void attn_k(
    const float* __restrict__ ent, const int* __restrict__ obs,
    const ushort_t* __restrict__ fc1w, const float* __restrict__ fc1b,
    const ushort_t* __restrict__ inw, ushort_t* __restrict__ attn_out) {
  __shared__ ushort_t x1s[64 * 264];
  __shared__ ushort_t ks[64 * 264];
  __shared__ ushort_t vs[64 * 264];
  __shared__ ushort_t wbuf[256 * 40];
  __shared__ ushort_t es[64 * 136];
  __shared__ float qs[8 * 256];
  __shared__ float lg[32 * 64];
  __shared__ int oms[512];

  const long b = blockIdx.x;
  const int tid = threadIdx.x;
  const int lane = tid & 63, wid = tid >> 6;
  const int mf = wid & 3, nh = wid >> 2;
  const int fr = lane & 15, kb = (lane >> 4) * 8, rb = (lane >> 4) * 4;

  oms[tid] = obs[b * 4096 + tid];
  for (int c = tid; c < 1024; c += 512) {
    int row = c >> 4, kc = (c & 15) * 8;
    *reinterpret_cast<s16x8*>(&es[row * 136 + kc]) =
        ld8f(&ent[b * 8192 + row * 128 + kc]);
  }
  __syncthreads();

  {
    f32x4 a1[8];
#pragma unroll
    for (int i = 0; i < 8; i++) a1[i] = (f32x4){0.f, 0.f, 0.f, 0.f};
    for (int k0 = 0; k0 < 128; k0 += 32) {
      __syncthreads();
      for (int c = tid; c < 1024; c += 512) {
        int row = c >> 2, kc = (c & 3) * 8;
        *reinterpret_cast<s16x8*>(&wbuf[row * 40 + kc]) =
            *reinterpret_cast<const s16x8*>(&fc1w[row * 128 + k0 + kc]);
      }
      __syncthreads();
      s16x8 af = *reinterpret_cast<const s16x8*>(&es[(mf * 16 + fr) * 136 + k0 + kb]);
#pragma unroll
      for (int ni = 0; ni < 8; ni++) {
        s16x8 wf = *reinterpret_cast<const s16x8*>(&wbuf[(nh * 128 + ni * 16 + fr) * 40 + kb]);
        a1[ni] = MFMA16(af, wf, a1[ni]);
      }
    }
#pragma unroll
    for (int ni = 0; ni < 8; ni++) {
      int col = nh * 128 + ni * 16 + fr;
      float bv = fc1b[col];
#pragma unroll
      for (int rr = 0; rr < 4; rr++) {
        int row = mf * 16 + rb + rr;
        x1s[row * 264 + col] = f2us(fmaxf(a1[ni][rr] + bv, 0.0f));
      }
    }
  }
  {
    f32x4 a2[8];
#pragma unroll
    for (int i = 0; i < 8; i++) a2[i] = (f32x4){0.f, 0.f, 0.f, 0.f};
    for (int k0 = 0; k0 < 256; k0 += 32) {
      __syncthreads();
      for (int c = tid; c < 1024; c += 512) {
        int row = c >> 2, kc = (c & 3) * 8;
        *reinterpret_cast<s16x8*>(&wbuf[row * 40 + kc]) =
            *reinterpret_cast<const s16x8*>(&inw[65536 + row * 256 + k0 + kc]);
      }
      __syncthreads();
      s16x8 af = *reinterpret_cast<const s16x8*>(&x1s[(mf * 16 + fr) * 264 + k0 + kb]);
#pragma unroll
      for (int ni = 0; ni < 8; ni++) {
        s16x8 wf = *reinterpret_cast<const s16x8*>(&wbuf[(nh * 128 + ni * 16 + fr) * 40 + kb]);
        a2[ni] = MFMA16(af, wf, a2[ni]);
      }
    }
#pragma unroll
    for (int ni = 0; ni < 8; ni++) {
      int col = nh * 128 + ni * 16 + fr;
#pragma unroll
      for (int rr = 0; rr < 4; rr++) ks[(mf * 16 + rb + rr) * 264 + col] = f2us(a2[ni][rr]);
    }
  }
  {
    f32x4 a3[8];
#pragma unroll
    for (int i = 0; i < 8; i++) a3[i] = (f32x4){0.f, 0.f, 0.f, 0.f};
    for (int k0 = 0; k0 < 256; k0 += 32) {
      __syncthreads();
      for (int c = tid; c < 1024; c += 512) {
        int row = c >> 2, kc = (c & 3) * 8;
        *reinterpret_cast<s16x8*>(&wbuf[row * 40 + kc]) =
            *reinterpret_cast<const s16x8*>(&inw[131072 + row * 256 + k0 + kc]);
      }
      __syncthreads();
      s16x8 af = *reinterpret_cast<const s16x8*>(&x1s[(mf * 16 + fr) * 264 + k0 + kb]);
#pragma unroll
      for (int ni = 0; ni < 8; ni++) {
        s16x8 wf = *reinterpret_cast<const s16x8*>(&wbuf[(nh * 128 + ni * 16 + fr) * 40 + kb]);
        a3[ni] = MFMA16(af, wf, a3[ni]);
      }
    }
#pragma unroll
    for (int ni = 0; ni < 8; ni++) {
      int col = nh * 128 + ni * 16 + fr;
#pragma unroll
      for (int rr = 0; rr < 4; rr++) vs[(mf * 16 + rb + rr) * 264 + col] = f2us(a3[ni][rr]);
    }
  }
  {
    f32x4 aq[2];
    aq[0] = (f32x4){0.f, 0.f, 0.f, 0.f};
    aq[1] = (f32x4){0.f, 0.f, 0.f, 0.f};
    for (int k0 = 0; k0 < 256; k0 += 32) {
      __syncthreads();
      for (int c = tid; c < 1024; c += 512) {
        int row = c >> 2, kc = (c & 3) * 8;
        *reinterpret_cast<s16x8*>(&wbuf[row * 40 + kc]) =
            *reinterpret_cast<const s16x8*>(&inw[row * 256 + k0 + kc]);
      }
      __syncthreads();
      s16x8 af = *reinterpret_cast<const s16x8*>(&x1s[fr * 264 + k0 + kb]);
#pragma unroll
      for (int i = 0; i < 2; i++) {
        int nf2 = wid * 2 + i;
        s16x8 wf = *reinterpret_cast<const s16x8*>(&wbuf[(nf2 * 16 + fr) * 40 + kb]);
        aq[i] = MFMA16(af, wf, aq[i]);
      }
    }
#pragma unroll
    for (int i = 0; i < 2; i++) {
#pragma unroll
      for (int rr = 0; rr < 4; rr++) {
        int row = rb + rr;
        if (row < 8) qs[row * 256 + (wid * 2 + i) * 16 + fr] = aq[i][rr] * 0.125f;
      }
    }
  }
  __syncthreads();

  for (int i = 0; i < 4; i++) {
    int idx = tid + 512 * i;
    int a = idx >> 8, h = (idx >> 6) & 3, e = idx & 63;
    const float* qrow = &qs[a * 256 + h * 64];
    const ushort_t* krow = &ks[e * 264 + h * 64];
    float s = 0.0f;
    for (int d = 0; d < 64; d++) s += qrow[d] * us2f(krow[d]);
    lg[(a * 4 + h) * 64 + e] = (oms[a * 64 + e] != 0) ? -1.0e30f : s;
  }
  __syncthreads();
  if (tid < 32) {
    int a = tid >> 2;
    float* row = &lg[tid * 64];
    bool dead = true;
    for (int e = 0; e < 64; e++)
      if (oms[a * 64 + e] == 0) { dead = false; break; }
    if (dead) {
      for (int e = 0; e < 64; e++) row[e] = 0.0f;
    } else {
      float mx = -1.0e30f;
      for (int e = 0; e < 64; e++) mx = fmaxf(mx, row[e]);
      float sum = 0.0f;
      for (int e = 0; e < 64; e++) { float ex = __expf(row[e] - mx); row[e] = ex; sum += ex; }
      float inv = 1.0f / sum;
      for (int e = 0; e < 64; e++) row[e] *= inv;
    }
  }
  __syncthreads();
  for (int i = 0; i < 4; i++) {
    int idx = tid + 512 * i;
    int a = idx >> 8, d = idx & 255, h = d >> 6;
    const float* wrow = &lg[(a * 4 + h) * 64];
    float s = 0.0f;
    for (int e = 0; e < 64; e++) s += wrow[e] * us2f(vs[e * 264 + d]);
    attn_out[((long)b * 8 + a) * 256 + d] = f2us(s);
  }
}

// ---------------------------------------------------------------------------
// GRU scan v2: 32 blocks = mdl(2) x chain-half(2) x col-slice(8).
// whh slice (96x256 bf16 = 50KB) LDS-RESIDENT for the whole scan.
// h exchanged per step via double-buffered bf16 hx[2][256x256] per module,
// device-scope grid barrier (monotone counter, memset before launch).
// ---------------------------------------------------------------------------
__global__ __launch_bounds__(512) void gru2_k(
    const ushort_t* __restrict__ gi_q, const ushort_t* __restrict__ gi_p,
    const ushort_t* __restrict__ whhb_q, const ushort_t* __restrict__ whhb_p,
    const float* __restrict__ bhh_q, const float* __restrict__ bhh_p,
    const float* __restrict__ h0_q, const float* __restrict__ h0_p,
    float* __restrict__ hs_q, float* __restrict__ hs_p,
    ushort_t* __restrict__ hx, unsigned* __restrict__ bar) {
  __shared__ ushort_t hst[128 * 264];   // 67,584 B
  __shared__ ushort_t wsl[96 * 264];    // 50,688 B
  const int bid = blockIdx.x;
  const int mdl = bid >> 4, mh = (bid >> 3) & 1, cs = bid & 7;
  const int c0 = cs * 32;
  const ushort_t* gi = mdl ? gi_p : gi_q;
  const ushort_t* whh = mdl ? whhb_p : whhb_q;
  const float* bhh = mdl ? bhh_p : bhh_q;
  const float* h0 = mdl ? h0_p : h0_q;
  float* hs = mdl ? hs_p : hs_q;
  ushort_t* hx0 = hx + (long)mdl * 131072;
  ushort_t* hx1 = hx0 + 65536;

  const int tid = threadIdx.x;
  const int lane = tid & 63, w = tid >> 6;
  const int fr = lane & 15, kb = (lane >> 4) * 8, rb = (lane >> 4) * 4;

  // whh slice -> LDS (row r = g*32+ci maps to whh row g*256+c0+ci)
  for (int c = tid; c < 96 * 32; c += 512) {
    int r = c >> 5, kc = (c & 31) * 8;
    int g = r >> 5, ci = r & 31;
    *reinterpret_cast<s16x8*>(&wsl[r * 264 + kc]) =
        *reinterpret_cast<const s16x8*>(&whh[(long)(g * 256 + c0 + ci) * 256 + kc]);
  }

  float hreg[2][4], bh[3][2];
  int chn[4];
#pragma unroll
  for (int rr = 0; rr < 4; rr++) chn[rr] = mh * 128 + w * 16 + rb + rr;
#pragma unroll
  for (int cc = 0; cc < 2; cc++) {
    int col = c0 + cc * 16 + fr;
#pragma unroll
    for (int rr = 0; rr < 4; rr++) hreg[cc][rr] = h0[chn[rr] * 256 + col];
#pragma unroll
    for (int g = 0; g < 3; g++) bh[g][cc] = bhh[g * 256 + col];
  }
  // publish initial h into hx0
#pragma unroll
  for (int cc = 0; cc < 2; cc++) {
    int col = c0 + cc * 16 + fr;
#pragma unroll
    for (int rr = 0; rr < 4; rr++) hx0[chn[rr] * 256 + col] = f2us(hreg[cc][rr]);
  }
  __threadfence();
  __syncthreads();
  unsigned tgt = 32;
  if (tid == 0) {
    __hip_atomic_fetch_add(bar, 1u, __ATOMIC_RELEASE, __HIP_MEMORY_SCOPE_AGENT);
    while (__hip_atomic_load(bar, __ATOMIC_ACQUIRE, __HIP_MEMORY_SCOPE_AGENT) < tgt)
      __builtin_amdgcn_s_sleep(8);
  }
  __syncthreads();

  for (int t = 0; t < 64; t++) {
    const ushort_t* hr = (t & 1) ? hx1 : hx0;
    ushort_t* hw = (t & 1) ? hx0 : hx1;
    // prefetch gi for this step (independent of h)
    ushort_t gv[2][4][3];
    long gib[4];
#pragma unroll
    for (int rr = 0; rr < 4; rr++) {
      int bs = chn[rr] >> 3, na = chn[rr] & 7;
      gib[rr] = (long)(bs * 64 + t) * 8 + na;
    }
#pragma unroll
    for (int cc = 0; cc < 2; cc++) {
      int col = c0 + cc * 16 + fr;
#pragma unroll
      for (int rr = 0; rr < 4; rr++)
#pragma unroll
        for (int g = 0; g < 3; g++)
          gv[cc][rr][g] = gi[gib[rr] * 768 + g * 256 + col];
    }
    // stage my chain-half of h (64KB)
    for (int c = tid; c < 128 * 32; c += 512) {
      int r = c >> 5, kc = (c & 31) * 8;
      *reinterpret_cast<s16x8*>(&hst[r * 264 + kc]) =
          *reinterpret_cast<const s16x8*>(&hr[(mh * 128 + r) * 256 + kc]);
    }
    __syncthreads();
    f32x4 acc[6];
#pragma unroll
    for (int i = 0; i < 6; i++) acc[i] = (f32x4){0.f, 0.f, 0.f, 0.f};
#pragma unroll
    for (int k0 = 0; k0 < 256; k0 += 32) {
      s16x8 a = *reinterpret_cast<const s16x8*>(&hst[(w * 16 + fr) * 264 + k0 + kb]);
#pragma unroll
      for (int nf = 0; nf < 6; nf++) {
        int g = nf >> 1, cc = nf & 1;
        s16x8 b = *reinterpret_cast<const s16x8*>(
            &wsl[(g * 32 + cc * 16 + fr) * 264 + k0 + kb]);
        acc[nf] = MFMA16(a, b, acc[nf]);  // acc[g*2+cc]
      }
    }
    // epilogue: gates + h update + publish
#pragma unroll
    for (int cc = 0; cc < 2; cc++) {
      int col = c0 + cc * 16 + fr;
#pragma unroll
      for (int rr = 0; rr < 4; rr++) {
        float r_ = sigm(us2f(gv[cc][rr][0]) + acc[0 + cc][rr] + bh[0][cc]);
        float z_ = sigm(us2f(gv[cc][rr][1]) + acc[2 + cc][rr] + bh[1][cc]);
        float n_ = tanh_f(us2f(gv[cc][rr][2]) + r_ * (acc[4 + cc][rr] + bh[2][cc]));
        float hn = (1.0f - z_) * n_ + z_ * hreg[cc][rr];
        hreg[cc][rr] = hn;
        hw[chn[rr] * 256 + col] = f2us(hn);
        hs[gib[rr] * 256 + col] = hn;
      }
    }
    __threadfence();
    __syncthreads();
    tgt += 32;
    if (tid == 0) {
      __hip_atomic_fetch_add(bar, 1u, __ATOMIC_RELEASE, __HIP_MEMORY_SCOPE_AGENT);
      while (__hip_atomic_load(bar, __ATOMIC_ACQUIRE, __HIP_MEMORY_SCOPE_AGENT) < tgt)
        __builtin_amdgcn_s_sleep(8);
    }
    __syncthreads();
  }
}

// ---------------------------------------------------------------------------
extern "C" void kernel_launch(void* const* d_in, const int* in_sizes, int n_in,
                              void* d_out, int out_size, void* d_ws, size_t ws_size,
                              hipStream_t stream) {
  (void)in_sizes; (void)n_in; (void)out_size; (void)ws_size;

  const float* entities = (const float*)d_in[0];
  const int* obs = (const int*)d_in[1];
  const int* em = (const int*)d_in[2];
  const float* hidq = (const float*)d_in[3];
  const float* hidp = (const float*)d_in[4];
  const float* q_fc1_w = (const float*)d_in[5];
  const float* q_fc1_b = (const float*)d_in[6];
  const float* q_fc2_w = (const float*)d_in[7];
  const float* q_fc2_b = (const float*)d_in[8];
  const float* q_wih = (const float*)d_in[9];
  const float* q_whh = (const float*)d_in[10];
  const float* q_bih = (const float*)d_in[11];
  const float* q_bhh = (const float*)d_in[12];
  const float* q_fcq_w = (const float*)d_in[13];
  const float* q_fcq_b = (const float*)d_in[14];
  const float* q_fcpi_w = (const float*)d_in[15];
  const float* q_fcpi_b = (const float*)d_in[16];
  const float* p_fc1_w = (const float*)d_in[17];
  const float* p_fc1_b = (const float*)d_in[18];
  const float* p_fc2_w = (const float*)d_in[19];
  const float* p_fc2_b = (const float*)d_in[20];
  const float* p_wih = (const float*)d_in[21];
  const float* p_whh = (const float*)d_in[22];
  const float* p_bih = (const float*)d_in[23];
  const float* p_bhh = (const float*)d_in[24];
  const float* p_fcpi_w = (const float*)d_in[27];
  const float* p_fcpi_b = (const float*)d_in[28];
  const float* inw = (const float*)d_in[29];
  const float* outw = (const float*)d_in[30];
  const float* outb = (const float*)d_in[31];

  // ws (bf16 elems): R0 | R1 | giq | gip | conv'd weights
  ushort_t* ws = (ushort_t*)d_ws;
  ushort_t* R0 = ws;                         // 4,194,304
  ushort_t* R1 = ws + 4194304l;              // 4,194,304
  ushort_t* giq = ws + 8388608l;             // 12,582,912
  ushort_t* gip = ws + 20971520l;            // 12,582,912
  ushort_t* wcv = ws + 33554432l;            // 622,592
  ushort_t* wbq = wcv;                       // whh_q bf16
  ushort_t* wbp = wcv + 196608l;             // whh_p bf16
  ushort_t* wf1 = wcv + 393216l;             // q_fc1_w bf16
  ushort_t* win = wcv + 425984l;             // q_attn_in_w bf16
  // gru h-exchange overlays R0 (free after gemm 7): 262,144 ushorts + counter
  ushort_t* hx = R0;                         // [2][2][65536]
  unsigned* bar = (unsigned*)(R0 + 262144l); // 64B counter region

  // Outputs (f32)
  float* out = (float*)d_out;
  float* o_q = out;
  float* o_pi = out + 1048576l;
  float* o_piA = out + 2097152l;
  float* o_hq = out + 3145728l;
  float* o_hp = out + 7340032l;

  // 0) pre-convert hot weights to bf16
  conv_k<<<608, 256, 0, stream>>>(q_whh, p_whh, q_fc1_w, inw, wcv);
  // 1) q-module front-end -> R0 (bf16)
  attn_k<<<2048, 512, 0, stream>>>(entities, obs, wf1, q_fc1_b, win, R0);
  // 2) x2 = mask0(attn @ outw^T + outb) -> R1
  gemm_k<128, 2, 0, 0, 0, 0><<<dim3(128, 2), 256, 0, stream>>>(R0, outw, outb, em, R1, 16384, 256, 256);
  // 3) x3q = relu(x2 @ fc2^T + b) -> R0
  gemm_k<128, 0, 0, 1, 0, 0><<<dim3(128, 2), 256, 0, stream>>>(R1, q_fc2_w, q_fc2_b, em, R0, 16384, 256, 256);
  // 4) gi_q = x3q @ wih^T + bih
  gemm_k<128, 0, 0, 0, 0, 0><<<dim3(128, 6), 256, 0, stream>>>(R0, q_wih, q_bih, em, giq, 16384, 768, 256);
  // 5) x1p = relu(e[:, :8] @ fc1^T + b) -> R1
  gemm_k<128, 0, 1, 1, 1, 0><<<dim3(128, 2), 256, 0, stream>>>(entities, p_fc1_w, p_fc1_b, em, R1, 16384, 256, 128);
  // 6) x3p = relu(x1p @ fc2^T + b) -> R0
  gemm_k<128, 0, 0, 1, 0, 0><<<dim3(128, 2), 256, 0, stream>>>(R1, p_fc2_w, p_fc2_b, em, R0, 16384, 256, 256);
  // 7) gi_p
  gemm_k<128, 0, 0, 0, 0, 0><<<dim3(128, 6), 256, 0, stream>>>(R0, p_wih, p_bih, em, gip, 16384, 768, 256);
  // 8) GRU scan v2 (R0 now free -> hx/bar overlay; zero the barrier counter)
  hipMemsetAsync(bar, 0, 64, stream);
  gru2_k<<<32, 512, 0, stream>>>(giq, gip, wbq, wbp, q_bhh, p_bhh, hidq, hidp,
                                 o_hq, o_hp, hx, bar);
  // 9) heads
  gemm_k<64, 2, 0, 0, 1, 1><<<dim3(128, 1), 256, 0, stream>>>(o_hq, q_fcq_w, q_fcq_b, em, o_q, 16384, 64, 256);
  gemm_k<64, 3, 0, 0, 1, 1><<<dim3(128, 1), 256, 0, stream>>>(o_hq, q_fcpi_w, q_fcpi_b, em, o_pi, 16384, 64, 256);
  gemm_k<64, 3, 0, 0, 1, 1><<<dim3(128, 1), 256, 0, stream>>>(o_hp, p_fcpi_w, p_fcpi_b, em, o_piA, 16384, 64, 256);
}

// Round 5
// 556.871 us; speedup vs baseline: 3.0146x; 2.2179x over previous
//
#include <hip/hip_runtime.h>

typedef unsigned short ushort_t;  // raw bf16 bits
typedef __attribute__((ext_vector_type(4))) float f32x4;
typedef __attribute__((ext_vector_type(8))) short s16x8;
typedef __attribute__((ext_vector_type(4))) short s16x4;

#define MFMA16(a, b, c) __builtin_amdgcn_mfma_f32_16x16x32_bf16((a), (b), (c), 0, 0, 0)

__device__ __forceinline__ float us2f(unsigned short u) {
  union { unsigned int i; float f; } v; v.i = ((unsigned int)u) << 16; return v.f;
}
__device__ __forceinline__ unsigned short f2us(float f) {
  union { float f; unsigned int i; } v; v.f = f;
  unsigned int x = v.i;
  return (unsigned short)((x + 0x7FFFu + ((x >> 16) & 1u)) >> 16);
}
// load 8 consecutive f32, round to 8 bf16
__device__ __forceinline__ s16x8 ld8f(const float* p) {
  f32x4 a = *reinterpret_cast<const f32x4*>(p);
  f32x4 b = *reinterpret_cast<const f32x4*>(p + 4);
  s16x8 r;
  r[0] = (short)f2us(a[0]); r[1] = (short)f2us(a[1]);
  r[2] = (short)f2us(a[2]); r[3] = (short)f2us(a[3]);
  r[4] = (short)f2us(b[0]); r[5] = (short)f2us(b[1]);
  r[6] = (short)f2us(b[2]); r[7] = (short)f2us(b[3]);
  return r;
}
__device__ __forceinline__ float sigm(float x) { return 1.0f / (1.0f + __expf(-x)); }
__device__ __forceinline__ float tanh_f(float x) {
  float e = __expf(-2.0f * fabsf(x));
  float t = (1.0f - e) / (1.0f + e);
  return x < 0.0f ? -t : t;
}

// ---------------------------------------------------------------------------
// f32 -> bf16 weight preconversion into ws:
// [0,196608) whh_q | [196608,393216) whh_p | [393216,425984) q_fc1_w |
// [425984,622592) q_attn_in_w
// ---------------------------------------------------------------------------
__global__ __launch_bounds__(256) void conv_k(
    const float* __restrict__ s0, const float* __restrict__ s1,
    const float* __restrict__ s2, const float* __restrict__ s3,
    ushort_t* __restrict__ d) {
  int i = blockIdx.x * 256 + threadIdx.x;
  if (i >= 155648) return;
  long e = (long)i * 4;
  const float* s; long off;
  if (e < 196608) { s = s0; off = e; }
  else if (e < 393216) { s = s1; off = e - 196608; }
  else if (e < 425984) { s = s2; off = e - 393216; }
  else { s = s3; off = e - 425984; }
  f32x4 v = *reinterpret_cast<const f32x4*>(s + off);
  s16x4 r;
  r[0] = (short)f2us(v[0]); r[1] = (short)f2us(v[1]);
  r[2] = (short)f2us(v[2]); r[3] = (short)f2us(v[3]);
  *reinterpret_cast<s16x4*>(d + e) = r;
}

// ---------------------------------------------------------------------------
// Generic GEMM: out[M,N] = epi(A[M,K] @ W[N,K]^T + bias)
// GIT: write bf16 output permuted to [t][g][cg][colw][16] for the GRU.
// ---------------------------------------------------------------------------
template <int BN, int EPI, int ROWSEL, int RELU, int AF32, int OF32, int GIT>
__global__ __launch_bounds__(256) void gemm_k(
    const void* __restrict__ A_, const float* __restrict__ W,
    const float* __restrict__ bias, const int* __restrict__ em,
    void* __restrict__ out_, int M, int N, int K) {
  constexpr int NF = (BN == 128) ? 4 : 2;
  const float* Af = (const float*)A_;
  const ushort_t* Ab = (const ushort_t*)A_;
  float* outf = (float*)out_;
  ushort_t* outb = (ushort_t*)out_;
  __shared__ ushort_t As[128 * 40];
  __shared__ ushort_t Ws[BN * 40];
  const int tid = threadIdx.x;
  const int lane = tid & 63;
  const int wid = tid >> 6;
  const int wm = wid & 1, wn = wid >> 1;
  const int m0 = blockIdx.x * 128;
  const int n0 = blockIdx.y * BN;
  const int fr = lane & 15;
  const int kb = (lane >> 4) * 8;

  f32x4 acc[4][NF];
#pragma unroll
  for (int i = 0; i < 4; i++)
#pragma unroll
    for (int j = 0; j < NF; j++) acc[i][j] = (f32x4){0.f, 0.f, 0.f, 0.f};

  for (int k0 = 0; k0 < K; k0 += 32) {
    __syncthreads();
    for (int c = tid; c < 512; c += 256) {
      int row = c >> 2, kc = (c & 3) * 8;
      int gr = m0 + row;
      long ar = ROWSEL ? ((long)(gr >> 3) * 64 + (gr & 7)) : (long)gr;
      s16x8 vv;
      if (AF32) vv = ld8f(&Af[ar * (long)K + k0 + kc]);
      else vv = *reinterpret_cast<const s16x8*>(&Ab[ar * (long)K + k0 + kc]);
      *reinterpret_cast<s16x8*>(&As[row * 40 + kc]) = vv;
    }
    for (int c = tid; c < BN * 4; c += 256) {
      int row = c >> 2, kc = (c & 3) * 8;
      *reinterpret_cast<s16x8*>(&Ws[row * 40 + kc]) =
          ld8f(&W[(long)(n0 + row) * K + k0 + kc]);
    }
    __syncthreads();
    s16x8 af[4], wf[NF];
#pragma unroll
    for (int mi = 0; mi < 4; mi++)
      af[mi] = *reinterpret_cast<const s16x8*>(&As[(wm * 64 + mi * 16 + fr) * 40 + kb]);
#pragma unroll
    for (int ni = 0; ni < NF; ni++)
      wf[ni] = *reinterpret_cast<const s16x8*>(&Ws[(wn * (BN / 2) + ni * 16 + fr) * 40 + kb]);
#pragma unroll
    for (int mi = 0; mi < 4; mi++)
#pragma unroll
      for (int ni = 0; ni < NF; ni++) acc[mi][ni] = MFMA16(af[mi], wf[ni], acc[mi][ni]);
  }

  const int rb = (lane >> 4) * 4;
#pragma unroll
  for (int ni = 0; ni < NF; ni++) {
    int col = n0 + wn * (BN / 2) + ni * 16 + fr;
    float bv = bias[col];
#pragma unroll
    for (int mi = 0; mi < 4; mi++) {
#pragma unroll
      for (int rr = 0; rr < 4; rr++) {
        int row = m0 + wm * 64 + mi * 16 + rb + rr;
        float v = acc[mi][ni][rr] + bv;
        if (RELU) v = fmaxf(v, 0.0f);
        if (EPI == 2 || EPI == 3) {
          if (em[(long)(row >> 3) * 64 + (row & 7)] != 0) v = (EPI == 2) ? 0.0f : -1.0e10f;
        }
        if (GIT) {
          int t = (row >> 3) & 63, bs = row >> 9, na = row & 7;
          int chain = bs * 8 + na;
          int g = col >> 8, cw = col & 255;
          outb[(((long)t * 3 + g) * 16 + (chain >> 4)) * 4096 + cw * 16 + (chain & 15)] =
              f2us(v);
        } else if (OF32) {
          outf[(long)row * N + col] = v;
        } else {
          outb[(long)row * N + col] = f2us(v);
        }
      }
    }
  }
}

// ---------------------------------------------------------------------------
// Fused q-module front-end (unchanged, passing)
// ---------------------------------------------------------------------------
__global__ __launch_bounds__(512) void attn_k(
    const float* __restrict__ ent, const int* __restrict__ obs,
    const ushort_t* __restrict__ fc1w, const float* __restrict__ fc1b,
    const ushort_t* __restrict__ inw, ushort_t* __restrict__ attn_out) {
  __shared__ ushort_t x1s[64 * 264];
  __shared__ ushort_t ks[64 * 264];
  __shared__ ushort_t vs[64 * 264];
  __shared__ ushort_t wbuf[256 * 40];
  __shared__ ushort_t es[64 * 136];
  __shared__ float qs[8 * 256];
  __shared__ float lg[32 * 64];
  __shared__ int oms[512];

  const long b = blockIdx.x;
  const int tid = threadIdx.x;
  const int lane = tid & 63, wid = tid >> 6;
  const int mf = wid & 3, nh = wid >> 2;
  const int fr = lane & 15, kb = (lane >> 4) * 8, rb = (lane >> 4) * 4;

  oms[tid] = obs[b * 4096 + tid];
  for (int c = tid; c < 1024; c += 512) {
    int row = c >> 4, kc = (c & 15) * 8;
    *reinterpret_cast<s16x8*>(&es[row * 136 + kc]) =
        ld8f(&ent[b * 8192 + row * 128 + kc]);
  }
  __syncthreads();

  {
    f32x4 a1[8];
#pragma unroll
    for (int i = 0; i < 8; i++) a1[i] = (f32x4){0.f, 0.f, 0.f, 0.f};
    for (int k0 = 0; k0 < 128; k0 += 32) {
      __syncthreads();
      for (int c = tid; c < 1024; c += 512) {
        int row = c >> 2, kc = (c & 3) * 8;
        *reinterpret_cast<s16x8*>(&wbuf[row * 40 + kc]) =
            *reinterpret_cast<const s16x8*>(&fc1w[row * 128 + k0 + kc]);
      }
      __syncthreads();
      s16x8 af = *reinterpret_cast<const s16x8*>(&es[(mf * 16 + fr) * 136 + k0 + kb]);
#pragma unroll
      for (int ni = 0; ni < 8; ni++) {
        s16x8 wf = *reinterpret_cast<const s16x8*>(&wbuf[(nh * 128 + ni * 16 + fr) * 40 + kb]);
        a1[ni] = MFMA16(af, wf, a1[ni]);
      }
    }
#pragma unroll
    for (int ni = 0; ni < 8; ni++) {
      int col = nh * 128 + ni * 16 + fr;
      float bv = fc1b[col];
#pragma unroll
      for (int rr = 0; rr < 4; rr++) {
        int row = mf * 16 + rb + rr;
        x1s[row * 264 + col] = f2us(fmaxf(a1[ni][rr] + bv, 0.0f));
      }
    }
  }
  {
    f32x4 a2[8];
#pragma unroll
    for (int i = 0; i < 8; i++) a2[i] = (f32x4){0.f, 0.f, 0.f, 0.f};
    for (int k0 = 0; k0 < 256; k0 += 32) {
      __syncthreads();
      for (int c = tid; c < 1024; c += 512) {
        int row = c >> 2, kc = (c & 3) * 8;
        *reinterpret_cast<s16x8*>(&wbuf[row * 40 + kc]) =
            *reinterpret_cast<const s16x8*>(&inw[65536 + row * 256 + k0 + kc]);
      }
      __syncthreads();
      s16x8 af = *reinterpret_cast<const s16x8*>(&x1s[(mf * 16 + fr) * 264 + k0 + kb]);
#pragma unroll
      for (int ni = 0; ni < 8; ni++) {
        s16x8 wf = *reinterpret_cast<const s16x8*>(&wbuf[(nh * 128 + ni * 16 + fr) * 40 + kb]);
        a2[ni] = MFMA16(af, wf, a2[ni]);
      }
    }
#pragma unroll
    for (int ni = 0; ni < 8; ni++) {
      int col = nh * 128 + ni * 16 + fr;
#pragma unroll
      for (int rr = 0; rr < 4; rr++) ks[(mf * 16 + rb + rr) * 264 + col] = f2us(a2[ni][rr]);
    }
  }
  {
    f32x4 a3[8];
#pragma unroll
    for (int i = 0; i < 8; i++) a3[i] = (f32x4){0.f, 0.f, 0.f, 0.f};
    for (int k0 = 0; k0 < 256; k0 += 32) {
      __syncthreads();
      for (int c = tid; c < 1024; c += 512) {
        int row = c >> 2, kc = (c & 3) * 8;
        *reinterpret_cast<s16x8*>(&wbuf[row * 40 + kc]) =
            *reinterpret_cast<const s16x8*>(&inw[131072 + row * 256 + k0 + kc]);
      }
      __syncthreads();
      s16x8 af = *reinterpret_cast<const s16x8*>(&x1s[(mf * 16 + fr) * 264 + k0 + kb]);
#pragma unroll
      for (int ni = 0; ni < 8; ni++) {
        s16x8 wf = *reinterpret_cast<const s16x8*>(&wbuf[(nh * 128 + ni * 16 + fr) * 40 + kb]);
        a3[ni] = MFMA16(af, wf, a3[ni]);
      }
    }
#pragma unroll
    for (int ni = 0; ni < 8; ni++) {
      int col = nh * 128 + ni * 16 + fr;
#pragma unroll
      for (int rr = 0; rr < 4; rr++) vs[(mf * 16 + rb + rr) * 264 + col] = f2us(a3[ni][rr]);
    }
  }
  {
    f32x4 aq[2];
    aq[0] = (f32x4){0.f, 0.f, 0.f, 0.f};
    aq[1] = (f32x4){0.f, 0.f, 0.f, 0.f};
    for (int k0 = 0; k0 < 256; k0 += 32) {
      __syncthreads();
      for (int c = tid; c < 1024; c += 512) {
        int row = c >> 2, kc = (c & 3) * 8;
        *reinterpret_cast<s16x8*>(&wbuf[row * 40 + kc]) =
            *reinterpret_cast<const s16x8*>(&inw[row * 256 + k0 + kc]);
      }
      __syncthreads();
      s16x8 af = *reinterpret_cast<const s16x8*>(&x1s[fr * 264 + k0 + kb]);
#pragma unroll
      for (int i = 0; i < 2; i++) {
        int nf2 = wid * 2 + i;
        s16x8 wf = *reinterpret_cast<const s16x8*>(&wbuf[(nf2 * 16 + fr) * 40 + kb]);
        aq[i] = MFMA16(af, wf, aq[i]);
      }
    }
#pragma unroll
    for (int i = 0; i < 2; i++) {
#pragma unroll
      for (int rr = 0; rr < 4; rr++) {
        int row = rb + rr;
        if (row < 8) qs[row * 256 + (wid * 2 + i) * 16 + fr] = aq[i][rr] * 0.125f;
      }
    }
  }
  __syncthreads();

  for (int i = 0; i < 4; i++) {
    int idx = tid + 512 * i;
    int a = idx >> 8, h = (idx >> 6) & 3, e = idx & 63;
    const float* qrow = &qs[a * 256 + h * 64];
    const ushort_t* krow = &ks[e * 264 + h * 64];
    float s = 0.0f;
    for (int d = 0; d < 64; d++) s += qrow[d] * us2f(krow[d]);
    lg[(a * 4 + h) * 64 + e] = (oms[a * 64 + e] != 0) ? -1.0e30f : s;
  }
  __syncthreads();
  if (tid < 32) {
    int a = tid >> 2;
    float* row = &lg[tid * 64];
    bool dead = true;
    for (int e = 0; e < 64; e++)
      if (oms[a * 64 + e] == 0) { dead = false; break; }
    if (dead) {
      for (int e = 0; e < 64; e++) row[e] = 0.0f;
    } else {
      float mx = -1.0e30f;
      for (int e = 0; e < 64; e++) mx = fmaxf(mx, row[e]);
      float sum = 0.0f;
      for (int e = 0; e < 64; e++) { float ex = __expf(row[e] - mx); row[e] = ex; sum += ex; }
      float inv = 1.0f / sum;
      for (int e = 0; e < 64; e++) row[e] *= inv;
    }
  }
  __syncthreads();
  for (int i = 0; i < 4; i++) {
    int idx = tid + 512 * i;
    int a = idx >> 8, d = idx & 255, h = d >> 6;
    const float* wrow = &lg[(a * 4 + h) * 64];
    float s = 0.0f;
    for (int e = 0; e < 64; e++) s += wrow[e] * us2f(vs[e * 264 + d]);
    attn_out[((long)b * 8 + a) * 256 + d] = f2us(s);
  }
}

// ---------------------------------------------------------------------------
// GRU scan v3: chain-split, ZERO inter-block communication.
// 32 blocks = 2 modules x 16 chain-groups (16 chains each). 1024 thr = 16
// waves; wave w owns h-cols [w*16, w*16+16). Weights: r,z gates in VGPRs
// (64/thread), n gate in LDS (128KB, XOR-swizzled [col][k]). h in f32 regs,
// staged to LDS as bf16 each step for the MFMA A operand. gi read from the
// GIT layout [t][g][cg][colw][16] with one s16x4 per (gate) per thread.
// ---------------------------------------------------------------------------
__global__ __launch_bounds__(1024) void gru3_k(
    const ushort_t* __restrict__ giT_q, const ushort_t* __restrict__ giT_p,
    const ushort_t* __restrict__ whhb_q, const ushort_t* __restrict__ whhb_p,
    const float* __restrict__ bhh_q, const float* __restrict__ bhh_p,
    const float* __restrict__ h0_q, const float* __restrict__ h0_p,
    float* __restrict__ hs_q, float* __restrict__ hs_p) {
  __shared__ ushort_t nw[256 * 256];  // n-gate weights, swizzled, 128KB
  __shared__ ushort_t hls[16 * 260];  // h staging, 8.3KB
  const int bid = blockIdx.x;
  const int mdl = bid >> 4, cg = bid & 15;
  const ushort_t* giT = mdl ? giT_p : giT_q;
  const ushort_t* whh = mdl ? whhb_p : whhb_q;
  const float* bhh = mdl ? bhh_p : bhh_q;
  const float* h0 = mdl ? h0_p : h0_q;
  float* hs = mdl ? hs_p : hs_q;

  const int tid = threadIdx.x;
  const int lane = tid & 63, w = tid >> 6;  // w in [0,16)
  const int fr = lane & 15, kb = (lane >> 4) * 8, rb = (lane >> 4) * 4;
  const int c0 = w * 16;
  const int col = c0 + fr;

  // r,z weight fragments -> VGPRs (col index = fr within wave's 16-col slice)
  s16x8 wrz[2][8];
#pragma unroll
  for (int g = 0; g < 2; g++)
#pragma unroll
    for (int ks = 0; ks < 8; ks++)
      wrz[g][ks] = *reinterpret_cast<const s16x8*>(
          &whh[(g * 256 + col) * 256 + ks * 32 + kb]);

  // n-gate weights -> LDS, XOR-swizzled: byte = row*512 + ((k*2) ^ ((row&7)<<4))
  char* nwb = (char*)nw;
  for (int c = tid; c < 8192; c += 1024) {
    int row = c >> 5, kc = (c & 31) * 8;
    *reinterpret_cast<s16x8*>(nwb + row * 512 + ((kc * 2) ^ ((row & 7) << 4))) =
        *reinterpret_cast<const s16x8*>(&whh[(512 + row) * 256 + kc]);
  }

  float h[4], bh[3];
#pragma unroll
  for (int rr = 0; rr < 4; rr++) h[rr] = h0[(cg * 16 + rb + rr) * 256 + col];
#pragma unroll
  for (int g = 0; g < 3; g++) bh[g] = bhh[g * 256 + col];

  long hsb[4];
#pragma unroll
  for (int rr = 0; rr < 4; rr++) {
    int chain = cg * 16 + rb + rr;
    hsb[rr] = ((long)((chain >> 3) * 64) * 8 + (chain & 7)) * 256 + col;  // + t*2048
  }

  for (int t = 0; t < 64; t++) {
    // gi loads (independent of h) — fully coalesced s16x4
    s16x4 gv[3];
#pragma unroll
    for (int g = 0; g < 3; g++)
      gv[g] = *reinterpret_cast<const s16x4*>(
          &giT[(((long)t * 3 + g) * 16 + cg) * 4096 + col * 16 + rb]);
    // stage h (bf16) for MFMA A operand
#pragma unroll
    for (int rr = 0; rr < 4; rr++) hls[(rb + rr) * 260 + col] = f2us(h[rr]);
    __syncthreads();
    f32x4 acc[3];
#pragma unroll
    for (int i = 0; i < 3; i++) acc[i] = (f32x4){0.f, 0.f, 0.f, 0.f};
#pragma unroll
    for (int ks = 0; ks < 8; ks++) {
      s16x8 a = *reinterpret_cast<const s16x8*>(&hls[fr * 260 + ks * 32 + kb]);
      acc[0] = MFMA16(a, wrz[0][ks], acc[0]);
      acc[1] = MFMA16(a, wrz[1][ks], acc[1]);
      s16x8 bn = *reinterpret_cast<const s16x8*>(
          nwb + col * 512 + (((ks * 32 + kb) * 2) ^ ((col & 7) << 4)));
      acc[2] = MFMA16(a, bn, acc[2]);
    }
    __syncthreads();  // protect hls before next step's writes
    // gate epilogue + publish hs
#pragma unroll
    for (int rr = 0; rr < 4; rr++) {
      float r_ = sigm(us2f((unsigned short)gv[0][rr]) + acc[0][rr] + bh[0]);
      float z_ = sigm(us2f((unsigned short)gv[1][rr]) + acc[1][rr] + bh[1]);
      float n_ = tanh_f(us2f((unsigned short)gv[2][rr]) + r_ * (acc[2][rr] + bh[2]));
      float hn = (1.0f - z_) * n_ + z_ * h[rr];
      h[rr] = hn;
      hs[hsb[rr] + (long)t * 2048] = hn;
    }
  }
}

// ---------------------------------------------------------------------------
extern "C" void kernel_launch(void* const* d_in, const int* in_sizes, int n_in,
                              void* d_out, int out_size, void* d_ws, size_t ws_size,
                              hipStream_t stream) {
  (void)in_sizes; (void)n_in; (void)out_size; (void)ws_size;

  const float* entities = (const float*)d_in[0];
  const int* obs = (const int*)d_in[1];
  const int* em = (const int*)d_in[2];
  const float* hidq = (const float*)d_in[3];
  const float* hidp = (const float*)d_in[4];
  const float* q_fc1_w = (const float*)d_in[5];
  const float* q_fc1_b = (const float*)d_in[6];
  const float* q_fc2_w = (const float*)d_in[7];
  const float* q_fc2_b = (const float*)d_in[8];
  const float* q_wih = (const float*)d_in[9];
  const float* q_whh = (const float*)d_in[10];
  const float* q_bih = (const float*)d_in[11];
  const float* q_bhh = (const float*)d_in[12];
  const float* q_fcq_w = (const float*)d_in[13];
  const float* q_fcq_b = (const float*)d_in[14];
  const float* q_fcpi_w = (const float*)d_in[15];
  const float* q_fcpi_b = (const float*)d_in[16];
  const float* p_fc1_w = (const float*)d_in[17];
  const float* p_fc1_b = (const float*)d_in[18];
  const float* p_fc2_w = (const float*)d_in[19];
  const float* p_fc2_b = (const float*)d_in[20];
  const float* p_wih = (const float*)d_in[21];
  const float* p_whh = (const float*)d_in[22];
  const float* p_bih = (const float*)d_in[23];
  const float* p_bhh = (const float*)d_in[24];
  const float* p_fcpi_w = (const float*)d_in[27];
  const float* p_fcpi_b = (const float*)d_in[28];
  const float* inw = (const float*)d_in[29];
  const float* outw = (const float*)d_in[30];
  const float* outb = (const float*)d_in[31];

  // ws (bf16 elems): R0 | R1 | giq | gip | conv'd weights
  ushort_t* ws = (ushort_t*)d_ws;
  ushort_t* R0 = ws;                         // 4,194,304
  ushort_t* R1 = ws + 4194304l;              // 4,194,304
  ushort_t* giq = ws + 8388608l;             // 12,582,912 (GIT layout)
  ushort_t* gip = ws + 20971520l;            // 12,582,912 (GIT layout)
  ushort_t* wcv = ws + 33554432l;            // 622,592
  ushort_t* wbq = wcv;                       // whh_q bf16
  ushort_t* wbp = wcv + 196608l;             // whh_p bf16
  ushort_t* wf1 = wcv + 393216l;             // q_fc1_w bf16
  ushort_t* win = wcv + 425984l;             // q_attn_in_w bf16

  // Outputs (f32)
  float* out = (float*)d_out;
  float* o_q = out;
  float* o_pi = out + 1048576l;
  float* o_piA = out + 2097152l;
  float* o_hq = out + 3145728l;
  float* o_hp = out + 7340032l;

  // 0) pre-convert hot weights to bf16
  conv_k<<<608, 256, 0, stream>>>(q_whh, p_whh, q_fc1_w, inw, wcv);
  // 1) q-module front-end -> R0 (bf16)
  attn_k<<<2048, 512, 0, stream>>>(entities, obs, wf1, q_fc1_b, win, R0);
  // 2) x2 = mask0(attn @ outw^T + outb) -> R1
  gemm_k<128, 2, 0, 0, 0, 0, 0><<<dim3(128, 2), 256, 0, stream>>>(R0, outw, outb, em, R1, 16384, 256, 256);
  // 3) x3q = relu(x2 @ fc2^T + b) -> R0
  gemm_k<128, 0, 0, 1, 0, 0, 0><<<dim3(128, 2), 256, 0, stream>>>(R1, q_fc2_w, q_fc2_b, em, R0, 16384, 256, 256);
  // 4) gi_q = x3q @ wih^T + bih (GIT layout)
  gemm_k<128, 0, 0, 0, 0, 0, 1><<<dim3(128, 6), 256, 0, stream>>>(R0, q_wih, q_bih, em, giq, 16384, 768, 256);
  // 5) x1p = relu(e[:, :8] @ fc1^T + b) -> R1
  gemm_k<128, 0, 1, 1, 1, 0, 0><<<dim3(128, 2), 256, 0, stream>>>(entities, p_fc1_w, p_fc1_b, em, R1, 16384, 256, 128);
  // 6) x3p = relu(x1p @ fc2^T + b) -> R0
  gemm_k<128, 0, 0, 1, 0, 0, 0><<<dim3(128, 2), 256, 0, stream>>>(R1, p_fc2_w, p_fc2_b, em, R0, 16384, 256, 256);
  // 7) gi_p (GIT layout)
  gemm_k<128, 0, 0, 0, 0, 0, 1><<<dim3(128, 6), 256, 0, stream>>>(R0, p_wih, p_bih, em, gip, 16384, 768, 256);
  // 8) GRU scan v3 — chain-split, no inter-block sync
  gru3_k<<<32, 1024, 0, stream>>>(giq, gip, wbq, wbp, q_bhh, p_bhh, hidq, hidp,
                                  o_hq, o_hp);
  // 9) heads
  gemm_k<64, 2, 0, 0, 1, 1, 0><<<dim3(128, 1), 256, 0, stream>>>(o_hq, q_fcq_w, q_fcq_b, em, o_q, 16384, 64, 256);
  gemm_k<64, 3, 0, 0, 1, 1, 0><<<dim3(128, 1), 256, 0, stream>>>(o_hq, q_fcpi_w, q_fcpi_b, em, o_pi, 16384, 64, 256);
  gemm_k<64, 3, 0, 0, 1, 1, 0><<<dim3(128, 1), 256, 0, stream>>>(o_hp, p_fcpi_w, p_fcpi_b, em, o_piA, 16384, 64, 256);
}